// Round 13
// baseline (85.436 us; speedup 1.0000x reference)
//
#include <hip/hip_runtime.h>
#include <hip/hip_fp16.h>
#include <math.h>

#define N_NODES 50000
#define N_EDGES 800000
#define D_FEAT 64
#define XCHUNKS (N_NODES * D_FEAT / 8)   // 400000 x->f16 chunks (8 elems each)
#define RPB 32                           // rows per block (4 waves * 8 row-groups)
#define NBLK ((N_NODES + RPB - 1) / RPB) // 1563
#define ECAP 768                         // staged edges/block (6KB); Poisson(512)+11sigma -> never

// ---- f16 helpers ----
__device__ __forceinline__ unsigned pack2h(float a, float b) {
    __half2 h = __floats2half2_rn(a, b);
    return *reinterpret_cast<unsigned*>(&h);
}
__device__ __forceinline__ __half2 as_h2(unsigned u) {
    return *reinterpret_cast<__half2*>(&u);
}

// Fast ELU: native v_exp_f32 (abs threshold 0.765 makes expm1 precision moot).
__device__ __forceinline__ float elu_f(float x) {
    return x > 0.f ? x : (__expf(x) - 1.f);
}

// Prep: row_ptr lower-bound + x (f32) -> f16 table [N][64] (round-11 layout).
__global__ __launch_bounds__(256) void prep_kernel(const int* __restrict__ rows,
                                                   const float* __restrict__ x,
                                                   int* __restrict__ row_ptr,
                                                   unsigned short* __restrict__ xhf) {
    const int i = blockIdx.x * blockDim.x + threadIdx.x;
    if (i <= N_NODES) {
        int lo = 0, hi = N_EDGES;
        while (lo < hi) {
            int mid = (lo + hi) >> 1;
            if (rows[mid] < i) lo = mid + 1; else hi = mid;
        }
        row_ptr[i] = lo;
    }
    if (i < XCHUNKS) {
        const float4 f0 = *reinterpret_cast<const float4*>(x + (size_t)i * 8);
        const float4 f1 = *reinterpret_cast<const float4*>(x + (size_t)i * 8 + 4);
        uint4 w;
        w.x = pack2h(f0.x, f0.y);
        w.y = pack2h(f0.z, f0.w);
        w.z = pack2h(f1.x, f1.y);
        w.w = pack2h(f1.z, f1.w);
        *reinterpret_cast<uint4*>(xhf + (size_t)i * 8) = w;
    }
}

// One 4-edge step for one row-group (8 lanes/row, 8 f16 features per lane).
// One 64-lane gather instruction covers 8 edges (8 groups x 8 lanes x 16B).
template <bool MASKED>
__device__ __forceinline__ void edge_step4_lds(const char* __restrict__ hb,
                                               const int2* __restrict__ elds,
                                               int le, int le1, int boff,
                                               __half2& A0, __half2& A1,
                                               __half2& A2, __half2& A3,
                                               __half2& B0, __half2& B1,
                                               __half2& B2, __half2& B3) {
    int off[4]; unsigned v2[4];
    #pragma unroll
    for (int k = 0; k < 4; ++k) {
        const int t = le + k;
        const int idx = MASKED ? (t < le1 ? t : le1 - 1) : t;
        const int2 p = elds[idx];
        off[k] = p.x;
        v2[k]  = (unsigned)p.y;
        if (MASKED) v2[k] = (t < le1) ? v2[k] : 0u;
    }
    uint4 gg[4];
    #pragma unroll
    for (int k = 0; k < 4; ++k)
        gg[k] = *reinterpret_cast<const uint4*>(hb + (unsigned)(off[k] + boff));
    #pragma unroll
    for (int k = 0; k < 4; ++k) {
        const __half2 vv = as_h2(v2[k]);
        if (k & 1) {
            B0 = __hfma2(vv, as_h2(gg[k].x), B0);
            B1 = __hfma2(vv, as_h2(gg[k].y), B1);
            B2 = __hfma2(vv, as_h2(gg[k].z), B2);
            B3 = __hfma2(vv, as_h2(gg[k].w), B3);
        } else {
            A0 = __hfma2(vv, as_h2(gg[k].x), A0);
            A1 = __hfma2(vv, as_h2(gg[k].y), A1);
            A2 = __hfma2(vv, as_h2(gg[k].z), A2);
            A3 = __hfma2(vv, as_h2(gg[k].w), A3);
        }
    }
}

// SpMM layer over f16 h: 4 waves/block, 8 row-groups/wave (8 lanes per row,
// 8 f16 features per lane = 16B gather; 128B line per edge, 8 edges/instr).
// Block's contiguous edge range staged in LDS from cols/vals (rows sorted).
// !FUSE: h_out is f16 [N_NODES][64].  FUSE: h_out is f32 out = y @ W^T + b.
template <bool FUSE>
__global__ __launch_bounds__(256) void gcn_layer(
    const unsigned short* __restrict__ h_in,  // f16 [N_NODES][64]
    const int*   __restrict__ cols,
    const float* __restrict__ vals,
    const int*   __restrict__ row_ptr,
    const float* __restrict__ scalar_p,
    const float* __restrict__ W,        // [64,64] (FUSE only)
    const float* __restrict__ bvec,     // [64]    (FUSE only)
    void*        __restrict__ h_out)
{
    __shared__ int2     elds[ECAP];                    // 6 KB staged edges
    __shared__ unsigned Wh[FUSE ? 64 * 33 : 1];        // 8.4 KB f16 W pairs
    __shared__ char     ylds[FUSE ? 4 * 8 * 136 : 1];  // 4.35 KB packed-f16 y

    const int tid  = threadIdx.x;
    const int lane = tid & 63;
    const int wave = tid >> 6;
    const int g    = lane >> 3;          // row-group 0..7
    const int l8   = lane & 7;           // 16B feature chunk index
    const int boff = l8 * 16;

    // Stage this block's contiguous edge range: (col*128, half2{v,v}).
    const int rb  = blockIdx.x * RPB;
    const int rtop = (rb + RPB < N_NODES) ? rb + RPB : N_NODES;
    const int eb0 = row_ptr[rb];
    const int eb1 = row_ptr[rtop];
    const int cnt = min(eb1 - eb0, ECAP);
    for (int i = tid; i < cnt; i += 256) {
        const int   c = cols[eb0 + i];
        const float v = vals[eb0 + i];
        elds[i] = make_int2(c << 7, (int)pack2h(v, v));
    }
    if constexpr (FUSE) {
        for (int i = tid; i < 64 * 32; i += 256) {
            const int j = i >> 5, c = i & 31;
            Wh[j * 33 + c] = pack2h(W[j * 64 + 2 * c], W[j * 64 + 2 * c + 1]);
        }
    }
    __syncthreads();

    const int row = rb + wave * 8 + g;
    const float s  = scalar_p[0];
    int e0 = 0, e1 = 0;
    if (row < N_NODES) { e0 = row_ptr[row]; e1 = row_ptr[row + 1]; }
    const char* hb = (const char*)h_in;

    __half2 A0 = __floats2half2_rn(0.f, 0.f);
    __half2 A1 = A0, A2 = A0, A3 = A0, B0 = A0, B1 = A0, B2 = A0, B3 = A0;

    // Staged window (virtually always the whole row).
    const int ecap = eb0 + cnt;
    const int le0 = e0 - eb0;
    const int le1 = (e1 < ecap ? e1 : ecap) - eb0;
    int le = le0;
    for (; le + 4 <= le1; le += 4)
        edge_step4_lds<false>(hb, elds, le, le1, boff, A0, A1, A2, A3, B0, B1, B2, B3);
    if (le < le1)
        edge_step4_lds<true>(hb, elds, le, le1, boff, A0, A1, A2, A3, B0, B1, B2, B3);
    // Overflow beyond staged capacity (essentially never): scalar global path.
    for (int e = (e0 > ecap ? e0 : ecap); e < e1; ++e) {
        const int   c = cols[e];
        const float v = vals[e];
        const __half2 vv = as_h2(pack2h(v, v));
        const uint4 gg = *reinterpret_cast<const uint4*>(hb + (unsigned)((c << 7) + boff));
        A0 = __hfma2(vv, as_h2(gg.x), A0);
        A1 = __hfma2(vv, as_h2(gg.y), A1);
        A2 = __hfma2(vv, as_h2(gg.z), A2);
        A3 = __hfma2(vv, as_h2(gg.w), A3);
    }

    // Convert to f32, combine A+B chains, scale + ELU -> 8 features.
    float r[8];
    {
        const float2 p0 = __half22float2(A0), q0 = __half22float2(B0);
        const float2 p1 = __half22float2(A1), q1 = __half22float2(B1);
        const float2 p2 = __half22float2(A2), q2 = __half22float2(B2);
        const float2 p3 = __half22float2(A3), q3 = __half22float2(B3);
        r[0] = elu_f((p0.x + q0.x) * s); r[1] = elu_f((p0.y + q0.y) * s);
        r[2] = elu_f((p1.x + q1.x) * s); r[3] = elu_f((p1.y + q1.y) * s);
        r[4] = elu_f((p2.x + q2.x) * s); r[5] = elu_f((p2.y + q2.y) * s);
        r[6] = elu_f((p3.x + q3.x) * s); r[7] = elu_f((p3.y + q3.y) * s);
    }
    uint4 packed;
    packed.x = pack2h(r[0], r[1]);
    packed.y = pack2h(r[2], r[3]);
    packed.z = pack2h(r[4], r[5]);
    packed.w = pack2h(r[6], r[7]);

    if constexpr (!FUSE) {
        if (row < N_NODES)
            *reinterpret_cast<uint4*>((char*)h_out + (size_t)row * 128 + boff) = packed;
    } else {
        // Stage packed y row into LDS (pitch 136B: conflict-free writes).
        char* yw = ylds + wave * (8 * 136);
        *reinterpret_cast<uint4*>(yw + g * 136 + l8 * 16) = packed;
        asm volatile("s_waitcnt lgkmcnt(0)" ::: "memory");  // same-wave ds ordering

        const int j = lane;
        const float bj = bvec[j];
        float o[8];
        #pragma unroll
        for (int q = 0; q < 8; ++q) o[q] = bj;
        #pragma unroll
        for (int d0 = 0; d0 < 16; ++d0) {
            const float2 wA = __half22float2(as_h2(Wh[j * 33 + 2 * d0]));
            const float2 wB = __half22float2(as_h2(Wh[j * 33 + 2 * d0 + 1]));
            #pragma unroll
            for (int q = 0; q < 8; ++q) {
                const uint2 yy = *reinterpret_cast<const uint2*>(yw + q * 136 + d0 * 8);
                const float2 p0 = __half22float2(as_h2(yy.x));
                const float2 p1 = __half22float2(as_h2(yy.y));
                o[q] = fmaf(p0.x, wA.x, o[q]); o[q] = fmaf(p0.y, wA.y, o[q]);
                o[q] = fmaf(p1.x, wB.x, o[q]); o[q] = fmaf(p1.y, wB.y, o[q]);
            }
        }
        const int rbase = rb + wave * 8;
        float* outp = (float*)h_out;
        #pragma unroll
        for (int q = 0; q < 8; ++q)
            if (rbase + q < N_NODES)
                outp[(size_t)(rbase + q) * D_FEAT + j] = o[q];
    }
}

extern "C" void kernel_launch(void* const* d_in, const int* in_sizes, int n_in,
                              void* d_out, int out_size, void* d_ws, size_t ws_size,
                              hipStream_t stream) {
    const float* x       = (const float*)d_in[0];
    const int*   rows    = (const int*)  d_in[1];
    const int*   cols    = (const int*)  d_in[2];
    const float* vals    = (const float*)d_in[3];
    const float* scalars = (const float*)d_in[4];
    const float* W       = (const float*)d_in[5];
    const float* b       = (const float*)d_in[6];
    float* out = (float*)d_out;

    // ws layout: row_ptr | xhf (f16) | h1 (f16)   (~13 MB total)
    const size_t rp_b = (sizeof(int) * (N_NODES + 1) + 255) & ~size_t(255);
    const size_t xb_b = ((size_t)N_NODES * D_FEAT * 2 + 255) & ~size_t(255);

    int*            row_ptr = (int*)d_ws;
    unsigned short* xhf     = (unsigned short*)((char*)d_ws + rp_b);
    unsigned short* h1      = (unsigned short*)((char*)d_ws + rp_b + xb_b);

    prep_kernel<<<(XCHUNKS + 255) / 256, 256, 0, stream>>>(rows, x, row_ptr, xhf);

    gcn_layer<false><<<NBLK, 256, 0, stream>>>(
        xhf, cols, vals, row_ptr, scalars + 0, nullptr, nullptr, h1);
    gcn_layer<true><<<NBLK, 256, 0, stream>>>(
        h1, cols, vals, row_ptr, scalars + 1, W, b, out);
}